// Round 4
// baseline (164.847 us; speedup 1.0000x reference)
//
#include <hip/hip_runtime.h>
#include <cstddef>

typedef float f4 __attribute__((ext_vector_type(4)));

#define OUT_FEATS 4096
#define IN_FEATS  16384
#define NCOL4     (IN_FEATS / 4)   // 4096 float4 per row
#define EPS       1e-8f

#define W       16                 // columns owned per block (64 B per row)
#define BT      1024               // threads per block (16 waves)
#define NBLK    (IN_FEATS / W)     // 1024 blocks
#define KITER   16                 // rows per thread
#define GSTR    256                // row-groups per pass (BT/4)

// ---------------------------------------------------------------------------
// Fused single-read kernel, v2. Block b owns columns [16b, 16b+16):
// reads its stripe (4096 x 16 fp32 = 256 KiB) ONCE into registers
// (16 x f4 = 64 VGPRs per thread across 1024 threads), reduces its coeff
// slice locally, applies, nt-stores. 512 MiB total HBM traffic.
//
// Fixes vs v1: payload is 64 regs (not 128) and pinned live via empty asm
// so the compiler cannot rematerialize the A-loads; __launch_bounds__(1024,4)
// -> 128-VGPR cap -> 16 waves/CU.
// ---------------------------------------------------------------------------
__global__ void __launch_bounds__(BT, 4)
k_fused(const f4* __restrict__ A4,
        const float* __restrict__ v,
        f4* __restrict__ out) {
    __shared__ float vs[OUT_FEATS];   // staged v (16 KiB)
    __shared__ float red[16];         // per-wave ||v||^2 partials
    __shared__ f4    red2[64];        // 16 waves x 4 col-quads

    // XCD-chunked swizzle: 1024 blocks, 8 XCDs, 128 consecutive stripes/XCD
    const int b = (blockIdx.x & 7) * (NBLK / 8) + (blockIdx.x >> 3);

    const int T = threadIdx.x;
    const int q = T & 3;              // col-quad within the stripe
    const int g = T >> 2;             // row-group 0..255
    const int w = T >> 6;             // wave id 0..15
    const int c4 = b * (W / 4) + q;   // global float4 column index

    // ---- 1. stage v into LDS + ||v||^2 partials (1 f4 per thread) ----
    {
        const f4 x = ((const f4*)v)[T];
        ((f4*)vs)[T] = x;
        float vsq = x.x * x.x + x.y * x.y + x.z * x.z + x.w * x.w;
        #pragma unroll
        for (int off = 32; off > 0; off >>= 1) vsq += __shfl_down(vsq, off, 64);
        if ((T & 63) == 0) red[w] = vsq;
    }
    __syncthreads();

    // ---- 2. load payload, FMA into coeff-partial as loads land ----
    f4 a[KITER];
    f4 s = 0.f;
    const size_t base = (size_t)g * NCOL4 + c4;
    #pragma unroll
    for (int k = 0; k < KITER; ++k) {
        a[k] = A4[base + (size_t)k * GSTR * NCOL4];
        s += vs[g + GSTR * k] * a[k];
    }
    // pin payload live in VGPRs so the store phase can't re-load A
    #pragma unroll
    for (int k = 0; k < KITER; ++k)
        asm volatile("" : "+v"(a[k].x), "+v"(a[k].y), "+v"(a[k].z), "+v"(a[k].w));

    // ---- 3. reduce across the 16 lanes/wave sharing a col-quad ----
    #pragma unroll
    for (int off = 4; off <= 32; off <<= 1) {
        s.x += __shfl_xor(s.x, off, 64);
        s.y += __shfl_xor(s.y, off, 64);
        s.z += __shfl_xor(s.z, off, 64);
        s.w += __shfl_xor(s.w, off, 64);
    }
    if ((T & 63) < 4) red2[w * 4 + q] = s;
    __syncthreads();

    // ---- 4. final coeff for this thread's col-quad ----
    float denom = EPS;
    #pragma unroll
    for (int i = 0; i < 16; ++i) denom += red[i];
    f4 cf = red2[q];
    #pragma unroll
    for (int w2 = 1; w2 < 16; ++w2) cf += red2[w2 * 4 + q];
    cf = cf / denom;

    // ---- 5. apply rank-1 update + non-temporal store ----
    #pragma unroll
    for (int k = 0; k < KITER; ++k) {
        const f4 o = a[k] - vs[g + GSTR * k] * cf;
        __builtin_nontemporal_store(o, &out[base + (size_t)k * GSTR * NCOL4]);
    }
}

// ---------------------------------------------------------------------------
extern "C" void kernel_launch(void* const* d_in, const int* in_sizes, int n_in,
                              void* d_out, int out_size, void* d_ws, size_t ws_size,
                              hipStream_t stream) {
    const f4*    A4 = (const f4*)d_in[0];     // raw_update [4096, 16384] fp32
    const float* v  = (const float*)d_in[1];  // v [4096] fp32
    f4* out = (f4*)d_out;

    k_fused<<<NBLK, BT, 0, stream>>>(A4, v, out);
}

// Round 5
// 156.261 us; speedup vs baseline: 1.0549x; 1.0549x over previous
//
#include <hip/hip_runtime.h>
#include <cstddef>

typedef float f4 __attribute__((ext_vector_type(4)));

#define OUT_FEATS 4096
#define IN_FEATS  16384
#define NCOL4     (IN_FEATS / 4)   // 4096 float4 per row
#define EPS       1e-8f

// ---------------------------------------------------------------------------
// Kernel 1: split-K partial GEMV. partial[chunk][j] = sum_{r in chunk} v[r]*A[r][j]
// grid = (NCOL4/256, nchunk), block = 256. Per thread: 8 independent
// accumulators, 8 f4 loads in flight. Wave reads 1 KiB contiguous per instr.
// v[] is block-uniform -> scalar loads. Normal loads (leave A in L3).
// ---------------------------------------------------------------------------
__global__ void __launch_bounds__(256)
k_gemv(const f4* __restrict__ A4, const float* __restrict__ v,
       f4* __restrict__ partial, int rows_per_chunk) {
    const int col4 = blockIdx.x * 256 + threadIdx.x;
    const int r0 = blockIdx.y * rows_per_chunk;

    f4 acc[8];
    #pragma unroll
    for (int i = 0; i < 8; ++i) acc[i] = 0.f;

    size_t base = (size_t)r0 * NCOL4 + col4;
    #pragma unroll 8
    for (int rr = 0; rr < rows_per_chunk; rr += 8) {
        const f4 a0 = A4[base];
        const f4 a1 = A4[base + (size_t)1 * NCOL4];
        const f4 a2 = A4[base + (size_t)2 * NCOL4];
        const f4 a3 = A4[base + (size_t)3 * NCOL4];
        const f4 a4 = A4[base + (size_t)4 * NCOL4];
        const f4 a5 = A4[base + (size_t)5 * NCOL4];
        const f4 a6 = A4[base + (size_t)6 * NCOL4];
        const f4 a7 = A4[base + (size_t)7 * NCOL4];
        const int r = r0 + rr;
        acc[0] += v[r + 0] * a0;
        acc[1] += v[r + 1] * a1;
        acc[2] += v[r + 2] * a2;
        acc[3] += v[r + 3] * a3;
        acc[4] += v[r + 4] * a4;
        acc[5] += v[r + 5] * a5;
        acc[6] += v[r + 6] * a6;
        acc[7] += v[r + 7] * a7;
        base += (size_t)8 * NCOL4;
    }
    const f4 tot = ((acc[0] + acc[1]) + (acc[2] + acc[3])) +
                   ((acc[4] + acc[5]) + (acc[6] + acc[7]));
    partial[(size_t)blockIdx.y * NCOL4 + col4] = tot;
}

// ---------------------------------------------------------------------------
// Kernel 2: coeff[j] = (sum_c partial[c][j]) / (||v||^2 + eps). 16 blocks.
// ---------------------------------------------------------------------------
__global__ void __launch_bounds__(256)
k_reduce(const f4* __restrict__ partial, const float* __restrict__ v,
         f4* __restrict__ coeff, int nchunk) {
    __shared__ float red[4];
    const int T = threadIdx.x;
    float s = 0.f;
    const f4* v4 = (const f4*)v;
    #pragma unroll
    for (int i = 0; i < OUT_FEATS / 4 / 256; ++i) {
        const f4 x = v4[T + i * 256];
        s += x.x * x.x + x.y * x.y + x.z * x.z + x.w * x.w;
    }
    #pragma unroll
    for (int off = 32; off > 0; off >>= 1) s += __shfl_down(s, off, 64);
    if ((T & 63) == 0) red[T >> 6] = s;
    __syncthreads();
    const float denom = red[0] + red[1] + red[2] + red[3] + EPS;

    const int j4 = blockIdx.x * 256 + T;
    f4 acc = 0.f;
    #pragma unroll 8
    for (int c = 0; c < nchunk; ++c)
        acc += partial[(size_t)c * NCOL4 + j4];
    coeff[j4] = acc / denom;
}

// ---------------------------------------------------------------------------
// Kernel 3: out = A - v[i]*coeff[j]. 4 rows per block, grid 1024.
// Inner step: 4 A-loads + 4 coeff-loads in flight, then 4 nt stores
// (don't let the 256 MiB out stream evict A from L3).
// ---------------------------------------------------------------------------
#define AROWS 4
__global__ void __launch_bounds__(256)
k_apply(const f4* __restrict__ A4, const float* __restrict__ v,
        const f4* __restrict__ coeff, f4* __restrict__ out) {
    const int T = threadIdx.x;
    const int r0 = blockIdx.x * AROWS;
    #pragma unroll
    for (int r = 0; r < AROWS; ++r) {
        const int row = r0 + r;
        const float vr = v[row];
        const size_t base = (size_t)row * NCOL4 + T;
        #pragma unroll
        for (int j0 = 0; j0 < NCOL4 / 256; j0 += 4) {
            const f4 a0 = A4[base + (size_t)(j0 + 0) * 256];
            const f4 a1 = A4[base + (size_t)(j0 + 1) * 256];
            const f4 a2 = A4[base + (size_t)(j0 + 2) * 256];
            const f4 a3 = A4[base + (size_t)(j0 + 3) * 256];
            const f4 c0 = coeff[T + (j0 + 0) * 256];
            const f4 c1 = coeff[T + (j0 + 1) * 256];
            const f4 c2 = coeff[T + (j0 + 2) * 256];
            const f4 c3 = coeff[T + (j0 + 3) * 256];
            __builtin_nontemporal_store(a0 - vr * c0, &out[base + (size_t)(j0 + 0) * 256]);
            __builtin_nontemporal_store(a1 - vr * c1, &out[base + (size_t)(j0 + 1) * 256]);
            __builtin_nontemporal_store(a2 - vr * c2, &out[base + (size_t)(j0 + 2) * 256]);
            __builtin_nontemporal_store(a3 - vr * c3, &out[base + (size_t)(j0 + 3) * 256]);
        }
    }
}

// ---------------------------------------------------------------------------
extern "C" void kernel_launch(void* const* d_in, const int* in_sizes, int n_in,
                              void* d_out, int out_size, void* d_ws, size_t ws_size,
                              hipStream_t stream) {
    const f4*    A4 = (const f4*)d_in[0];     // raw_update [4096, 16384] fp32
    const float* v  = (const float*)d_in[1];  // v [4096] fp32
    f4* out = (f4*)d_out;

    // ws layout (floats): [0, 16384) coeff | [16384, ...) partials
    float* ws = (float*)d_ws;
    f4* coeff   = (f4*)ws;
    f4* partial = (f4*)(ws + IN_FEATS);

    const size_t avail_floats = ws_size / sizeof(float);
    int nchunk = 64;
    while (nchunk > 8 &&
           (size_t)IN_FEATS + (size_t)nchunk * IN_FEATS > avail_floats) {
        nchunk >>= 1;
    }
    const int rows_per_chunk = OUT_FEATS / nchunk;   // >= 64, divisible by 8

    dim3 g1(NCOL4 / 256, nchunk);
    k_gemv<<<g1, 256, 0, stream>>>(A4, v, partial, rows_per_chunk);

    k_reduce<<<NCOL4 / 256, 256, 0, stream>>>(partial, v, coeff, nchunk);

    k_apply<<<OUT_FEATS / AROWS, 256, 0, stream>>>(A4, v, coeff, out);
}